// Round 1
// baseline (2880.320 us; speedup 1.0000x reference)
//
#include <hip/hip_runtime.h>
#include <cstddef>
#include <cstdint>

// CT-LSTM right-to-left scan. B=16,P=8 -> 128 independent sequences, T=256,
// H=256, 7H=1792 gate rows, VOCAB=35, IDX_PAD=34.
//
// Decomposition:
//   z = [emb, h] @ W^T + b
//     = EW[event]           (precomputed: Emb @ W[:, :256]^T + b, 35x1792)
//     + h @ W[:, 256:]^T    (sequential part, f16 weights + v_dot2_f32_f16)
//
// scan kernel: 64 blocks x 256 threads, 2 seqs/block, thread j owns hidden
// index j (7 gate rows). h double-buffered in LDS (f16), one barrier/step.

typedef _Float16 hf;
typedef _Float16 h2 __attribute__((ext_vector_type(2)));
typedef _Float16 h8 __attribute__((ext_vector_type(8)));

#define HID 256
#define R7 1792
#define TT 256
#define NPAD 34

#define SVP(v, k) __builtin_shufflevector(v, v, 2*(k), 2*(k)+1)

__device__ __forceinline__ float fdot2_(h2 a, h2 b, float c) {
#if __has_builtin(__builtin_amdgcn_fdot2)
  return __builtin_amdgcn_fdot2(a, b, c, false);
#else
  return fmaf((float)a[0], (float)b[0], fmaf((float)a[1], (float)b[1], c));
#endif
}

__device__ __forceinline__ float sigf(float x) { return 1.0f / (1.0f + __expf(-x)); }
// stable tanh: overflow of exp -> inf -> 1; underflow -> -1.
__device__ __forceinline__ float tanh_f(float x) { return 1.0f - 2.0f / (__expf(2.0f * x) + 1.0f); }
__device__ __forceinline__ float softplusf(float x) {
  return fmaxf(x, 0.0f) + __logf(1.0f + __expf(-fabsf(x)));
}

// ---------------------------------------------------------------------------
// Repack W[:, 256:512] (fp32, row-major [1792][512]) into f16 layout
//   W2v[((c*7 + g)*256 + j) * 8 + e] = W[g*256 + j][256 + 8c + e]
// so the scan kernel's lane j does global_load_dwordx4 with lanes contiguous.
__global__ __launch_bounds__(256) void repack_kernel(const float* __restrict__ W,
                                                     h8* __restrict__ W2v) {
  int idx = blockIdx.x * 256 + threadIdx.x;  // [0, 57344)
  int jj  = idx & 255;
  int cg  = idx >> 8;   // [0, 224) = c*7 + g
  int g   = cg % 7;
  int c   = cg / 7;
  int r   = g * 256 + jj;
  const float* src = W + (size_t)r * 512 + 256 + 8 * c;
  h8 o;
#pragma unroll
  for (int e = 0; e < 8; ++e) o[e] = (hf)src[e];
  W2v[idx] = o;
}

// ---------------------------------------------------------------------------
// EW[e][r] = sum_k Emb[e][k] * W[r][k] + b[r]   (e<35, r<1792, k<256)
// One wave per 4 outputs; lanes split k (contiguous in both operands).
__global__ __launch_bounds__(256) void ew_kernel(const float* __restrict__ Emb,
                                                 const float* __restrict__ W,
                                                 const float* __restrict__ bias,
                                                 float* __restrict__ EW) {
  int wid  = (blockIdx.x * 256 + threadIdx.x) >> 6;
  int lane = threadIdx.x & 63;
  int o    = wid * 4;
#pragma unroll
  for (int q = 0; q < 4; ++q, ++o) {
    int e = o / R7;
    int r = o - e * R7;
    const float4 ev4 = *(const float4*)(Emb + e * HID + lane * 4);
    const float4 wv4 = *(const float4*)(W + (size_t)r * 512 + lane * 4);
    float acc = ev4.x * wv4.x + ev4.y * wv4.y + ev4.z * wv4.z + ev4.w * wv4.w;
#pragma unroll
    for (int m = 32; m >= 1; m >>= 1) acc += __shfl_xor(acc, m, 64);
    if (lane == 0) EW[o] = acc + bias[r];
  }
}

// ---------------------------------------------------------------------------
__global__ __launch_bounds__(256, 1) void scan_kernel(
    const int* __restrict__ event, const float* __restrict__ dtime,
    const float* __restrict__ EW, const h8* __restrict__ Wv,
    float* __restrict__ out) {
  const int j    = threadIdx.x;
  const int seq0 = blockIdx.x * 2;
  const int seq1 = seq0 + 1;

  __shared__ __align__(16) hf hls[2][2][HID];  // [buf][seq][idx]
  __shared__ int   evs[2][TT];
  __shared__ float dts[2][TT];

  evs[0][j] = event[seq0 * TT + j];
  evs[1][j] = event[seq1 * TT + j];
  dts[0][j] = dtime[seq0 * TT + j];
  dts[1][j] = dtime[seq1 * TT + j];
  hls[0][0][j] = (hf)0.0f;
  hls[0][1][j] = (hf)0.0f;
  __syncthreads();

  float cp0 = 0.f, cb0 = 0.f, cp1 = 0.f, cb1 = 0.f;
  int rb = 0;
  const size_t OS = 8355840;  // per-output-tensor stride (16*8*255*256)

  for (int i = TT - 1; i >= 1; --i) {
    const int   t   = i - 1;
    const int   ev0 = evs[0][i], ev1 = evs[1][i];
    const float dt0 = dts[0][i], dt1 = dts[1][i];

    float a0[7], a1[7];
    const float* E0 = EW + ev0 * R7 + j;
    const float* E1 = EW + ev1 * R7 + j;
#pragma unroll
    for (int g = 0; g < 7; ++g) { a0[g] = E0[g * HID]; a1[g] = E1[g * HID]; }

    const h8* hp0 = (const h8*)(&hls[rb][0][0]);
    const h8* hp1 = (const h8*)(&hls[rb][1][0]);
    const h8* wp  = Wv + j;
#pragma unroll 4
    for (int c = 0; c < 32; ++c) {
      const h8 hv0 = hp0[c];
      const h8 hv1 = hp1[c];
      const h2 p00 = SVP(hv0, 0), p01 = SVP(hv0, 1), p02 = SVP(hv0, 2), p03 = SVP(hv0, 3);
      const h2 p10 = SVP(hv1, 0), p11 = SVP(hv1, 1), p12 = SVP(hv1, 2), p13 = SVP(hv1, 3);
#pragma unroll
      for (int g = 0; g < 7; ++g) {
        const h8 w = wp[(c * 7 + g) * HID];
        const h2 q0 = SVP(w, 0), q1 = SVP(w, 1), q2 = SVP(w, 2), q3 = SVP(w, 3);
        float s0 = a0[g];
        s0 = fdot2_(q0, p00, s0);
        s0 = fdot2_(q1, p01, s0);
        s0 = fdot2_(q2, p02, s0);
        s0 = fdot2_(q3, p03, s0);
        a0[g] = s0;
        float s1 = a1[g];
        s1 = fdot2_(q0, p10, s1);
        s1 = fdot2_(q1, p11, s1);
        s1 = fdot2_(q2, p12, s1);
        s1 = fdot2_(q3, p13, s1);
        a1[g] = s1;
      }
    }

    float hn0, hn1;
    {  // seq0 epilogue
      float* o = out + (size_t)seq0 * 65280 + (size_t)t * HID + j;
      float gi = sigf(a0[0]), gf = sigf(a0[1]), go = sigf(a0[2]);
      float gz = tanh_f(a0[3]);
      float gib = sigf(a0[4]), gfb = sigf(a0[5]);
      float gd = softplusf(a0[6]);
      float cell = gf * cp0 + gi * gz;
      float cbar = gfb * cb0 + gib * gz;
      float hm   = go * tanh_f(cell);
      float dec  = __expf(-gd * dt0);
      float cim  = cbar + (cell - cbar) * dec;
      float him  = go * tanh_f(cim);
      float m    = (ev0 != NPAD) ? 1.0f : 0.0f;
      float cbm  = cbar * m;
      o[0] = cell; o[OS] = cbm; o[2 * OS] = gd; o[3 * OS] = go;
      o[4 * OS] = him * m; o[5 * OS] = hm;
      cp0 = cim * m; cb0 = cbm; hn0 = him * m;
    }
    {  // seq1 epilogue
      float* o = out + (size_t)seq1 * 65280 + (size_t)t * HID + j;
      float gi = sigf(a1[0]), gf = sigf(a1[1]), go = sigf(a1[2]);
      float gz = tanh_f(a1[3]);
      float gib = sigf(a1[4]), gfb = sigf(a1[5]);
      float gd = softplusf(a1[6]);
      float cell = gf * cp1 + gi * gz;
      float cbar = gfb * cb1 + gib * gz;
      float hm   = go * tanh_f(cell);
      float dec  = __expf(-gd * dt1);
      float cim  = cbar + (cell - cbar) * dec;
      float him  = go * tanh_f(cim);
      float m    = (ev1 != NPAD) ? 1.0f : 0.0f;
      float cbm  = cbar * m;
      o[0] = cell; o[OS] = cbm; o[2 * OS] = gd; o[3 * OS] = go;
      o[4 * OS] = him * m; o[5 * OS] = hm;
      cp1 = cim * m; cb1 = cbm; hn1 = him * m;
    }

    hls[rb ^ 1][0][j] = (hf)hn0;
    hls[rb ^ 1][1][j] = (hf)hn1;
    __syncthreads();
    rb ^= 1;
  }
}

extern "C" void kernel_launch(void* const* d_in, const int* in_sizes, int n_in,
                              void* d_out, int out_size, void* d_ws, size_t ws_size,
                              hipStream_t stream) {
  const int*   event = (const int*)d_in[0];
  const float* dtime = (const float*)d_in[1];
  const float* Emb   = (const float*)d_in[2];
  const float* W     = (const float*)d_in[3];
  const float* bias  = (const float*)d_in[4];
  float*       out   = (float*)d_out;

  char* ws   = (char*)d_ws;
  hf*   W2v  = (hf*)ws;                       // 57344 * 16 B = 917504 B
  float* EW  = (float*)(ws + 917504);         // 35*1792*4   = 250880 B

  repack_kernel<<<224, 256, 0, stream>>>(W, (h8*)W2v);
  ew_kernel<<<3920, 256, 0, stream>>>(Emb, W, bias, EW);
  scan_kernel<<<64, 256, 0, stream>>>(event, dtime, EW, (const h8*)W2v, out);
}